// Round 13
// baseline (3298.679 us; speedup 1.0000x reference)
//
#include <hip/hip_runtime.h>
#include <hip/hip_bf16.h>

#define VV 50257
#define DD 256
#define HH 512
#define BB 64
#define SS 512
#define H3 1536
#define NWG 32          // 2 batch-groups x 16 hidden-slices
#define NSL 16          // slices
#define SCOLS 32        // hidden cols per slice
#define UCOLS 96        // 3 gates x 32
#define UBYTES (64*UCOLS*16)   // 98304 B resident U slice image
#define SCRB 2048              // 4 waves x 512 B transpose scratch
#define HBYTES (BB*HH*2)       // 65536 B f16 h image [64][512]

typedef _Float16 f16x8 __attribute__((ext_vector_type(8)));
typedef _Float16 f16x4 __attribute__((ext_vector_type(4)));
typedef float f32x4 __attribute__((ext_vector_type(4)));
typedef unsigned int u32x4 __attribute__((ext_vector_type(4)));
typedef unsigned int u32x2 __attribute__((ext_vector_type(2)));

#define AS1 __attribute__((address_space(1)))
#define AS3 __attribute__((address_space(3)))
#define GLL16(g, s) __builtin_amdgcn_global_load_lds((const AS1 char*)(g), (AS3 char*)(s), 16, 0, 0)

// ---------------------------------------------------------------------------
// Pack W (f32 [256][1536]) -> f16 k-major
// ---------------------------------------------------------------------------
__global__ __launch_bounds__(256) void kPackW(const float* __restrict__ W,
                                              _Float16* __restrict__ wsW) {
    int idx = blockIdx.x * 256 + threadIdx.x;
    int kb = idx / H3, col = idx % H3;
    f16x8 v;
    #pragma unroll
    for (int e = 0; e < 8; ++e) v[e] = (_Float16)W[(size_t)(kb*8+e)*H3 + col];
    *(f16x8*)(wsW + (size_t)idx*8) = v;
}

// ---------------------------------------------------------------------------
// Pack U -> per-slice k-major images. Slice s: packed col pc = gi*32 + cl
// <- source col gi*512 + s*32 + cl.  Row kb: 96 cols x 16B.
// ---------------------------------------------------------------------------
__global__ __launch_bounds__(256) void kPackU(const float* __restrict__ U,
                                              _Float16* __restrict__ wsU) {
    int s = blockIdx.x;                            // 16 slices
    for (int idx = threadIdx.x; idx < 64*UCOLS; idx += 256) {
        int kb = idx / UCOLS, pc = idx % UCOLS;
        int gi = pc / SCOLS, cl = pc % SCOLS;
        int gcol = gi*HH + s*SCOLS + cl;
        f16x8 v;
        #pragma unroll
        for (int e = 0; e < 8; ++e) v[e] = (_Float16)U[(size_t)(kb*8+e)*H3 + gcol];
        *(f16x8*)(wsU + (size_t)s*(UBYTES/2) + (size_t)idx*8) = v;
    }
}

// maskbits[t] bit r = (tokens[r][t] != 0)
__global__ __launch_bounds__(256) void kMask(const int* __restrict__ tokens,
                                             unsigned long long* __restrict__ mb) {
    int t = blockIdx.x * 256 + threadIdx.x;
    if (t < SS) {
        unsigned long long m = 0ull;
        for (int r = 0; r < BB; ++r)
            m |= (unsigned long long)(tokens[r*SS + t] != 0) << r;
        mb[t] = m;
    }
}

// ---------------------------------------------------------------------------
// K1: xp[t][col][b] (f16) = (emb[tokens] @ W + b0)
// ---------------------------------------------------------------------------
__global__ __launch_bounds__(256) void k1_embed_proj(
    const int* __restrict__ tokens, const float* __restrict__ emb,
    const _Float16* __restrict__ wsW, const float* __restrict__ bias,
    _Float16* __restrict__ xp)
{
    const int s  = blockIdx.y;
    const int nt = blockIdx.x;
    const int tid = threadIdx.x;
    __shared__ _Float16 aLds[64 * 256];

    for (int c = tid; c < 64 * 32; c += 256) {
        int row = c >> 5, kc = c & 31;
        int tok = tokens[row * SS + s];
        const float* src = emb + (size_t)tok * DD + kc * 8;
        float4 f0 = *(const float4*)(src);
        float4 f1 = *(const float4*)(src + 4);
        f16x8 v;
        v[0]=(_Float16)f0.x; v[1]=(_Float16)f0.y; v[2]=(_Float16)f0.z; v[3]=(_Float16)f0.w;
        v[4]=(_Float16)f1.x; v[5]=(_Float16)f1.y; v[6]=(_Float16)f1.z; v[7]=(_Float16)f1.w;
        int byte = row * 512 + ((kc * 16) ^ ((row & 7) << 4));
        *(f16x8*)((char*)aLds + byte) = v;
    }
    __syncthreads();

    const int w = tid >> 6, l = tid & 63;
    const int l15 = l & 15, lk = l >> 4;
    const int colbase = nt * 128;
    f32x4 acc[8] = {};

    for (int ks = 0; ks < 8; ++ks) {
        int arow = 16 * w + l15;
        f16x8 aF = *(const f16x8*)((const char*)aLds + arow*512 + (((ks*32 + lk*8)*2) ^ ((arow & 7) << 4)));
        int kb = ks*4 + lk;
        #pragma unroll
        for (int ns = 0; ns < 8; ++ns) {
            int col = colbase + ns * 16 + l15;
            f16x8 bF = *(const f16x8*)(wsW + ((size_t)kb * H3 + col) * 8);
            acc[ns] = __builtin_amdgcn_mfma_f32_16x16x32_f16(aF, bF, acc[ns], 0, 0, 0);
        }
    }
    #pragma unroll
    for (int ns = 0; ns < 8; ++ns) {
        int col = colbase + ns * 16 + l15;
        float b0 = bias[col];
        f16x4 vv;
        #pragma unroll
        for (int i = 0; i < 4; ++i) vv[i] = (_Float16)(acc[ns][i] + b0);
        *(f16x4*)(xp + ((size_t)s * H3 + col) * BB + 16*w + lk*4) = vv;
    }
}

// ---------------------------------------------------------------------------
// K2: persistent GRU scan — in-band parity tags + speculative data sweep.
// 2 batch-groups x 16 slices; wave (mi,c) of WG (g,s) owns rows
// g*32+mi*16..+15, cols s*32+c*16..+15.  Per step: SPECULATIVE tagged data
// sweep (16KB, verified by bit14 tags) -> if tags fail, fall back to cheap
// sentinel wait (32 cluster flags) + bounded resweep loop -> MFMA -> gates
// -> tagged publish (dwordx2 via wave-local LDS transpose) -> sentinel.
// No vmcnt drains on the publish side, no barriers in the t-loop.
// ---------------------------------------------------------------------------
__global__ __launch_bounds__(256) void k2_scan(
    const _Float16* __restrict__ xp, const _Float16* __restrict__ wsU,
    const float* __restrict__ bias, const unsigned long long* __restrict__ maskbits,
    char* __restrict__ hpub, float* __restrict__ hlast,
    unsigned int* __restrict__ flags)
{
    extern __shared__ char uLds[];
    const int tid = threadIdx.x;
    const int g = blockIdx.x >> 4;              // batch group (0..1)
    const int s = blockIdx.x & 15;              // hidden slice (0..15)
    const int w = tid >> 6, l = tid & 63;
    const int l15 = l & 15, lk = l >> 4;
    const int mi = w >> 1, c = w & 1;
    const int rb = g*32 + mi*16;                // wave's row band
    const int j  = s*SCOLS + c*16 + l15;        // this thread's hidden col
    const int b0 = rb + lk*4;
    const int cluster = (g*2 + mi) << 5;        // 32 producer waves per cluster
    unsigned short* scr = (unsigned short*)(uLds + UBYTES + w*512);

    // stage resident U slice (24 x 4KB)
    {
        const char* src = (const char*)wsU + (size_t)s * UBYTES;
        #pragma unroll
        for (int base = 0; base < UBYTES; base += 4096)
            GLL16(src + base + tid*16, uLds + base + tid*16);
    }

    // prologue prefetch: xp(0) -> even slot, xp(1) -> odd slot
    f16x4 xpe0, xpe1, xpe2, xpo0, xpo1, xpo2;
    unsigned long long mbe, mbo;
    {
        const _Float16* x0 = xp;
        xpe0 = *(const f16x4*)(x0 + (0*HH + j)*BB + b0);
        xpe1 = *(const f16x4*)(x0 + (1*HH + j)*BB + b0);
        xpe2 = *(const f16x4*)(x0 + (2*HH + j)*BB + b0);
        const _Float16* x1 = xp + (size_t)H3 * BB;
        xpo0 = *(const f16x4*)(x1 + (0*HH + j)*BB + b0);
        xpo1 = *(const f16x4*)(x1 + (1*HH + j)*BB + b0);
        xpo2 = *(const f16x4*)(x1 + (2*HH + j)*BB + b0);
        mbe = maskbits[0];
        mbo = maskbits[1];
    }
    const float b1z = bias[H3 + j];
    const float b1r = bias[H3 + HH + j];
    const float b1h = bias[H3 + 2*HH + j];
    float hold[4] = {};
    __syncthreads();   // U staged (only barrier in kernel)

    auto step = [&](int t, f16x4 xz4, f16x4 xr4, f16x4 xh4,
                    unsigned long long mbv) __attribute__((always_inline)) {
        f32x4 az = {}, ar = {}, ah = {};
        if (t > 0) {
            const unsigned expm = ((t >> 1) & 1) ? 0x40004000u : 0u;
            const char* hsrc = hpub + (size_t)(t & 1) * HBYTES;
            unsigned long long hb = (unsigned long long)(hsrc + (rb + l15)*1024 + lk*16);
            u32x4 hf[16];

#define SWEEP(okvar)                                                          \
            {                                                                 \
_Pragma("unroll")                                                             \
                /* issue 16 loads, wait, tag-check */                         \
                ;                                                             \
            }
            // --- speculative first sweep ---
            bool ok;
            {
#define LDH(i, off) asm volatile("global_load_dwordx4 %0, %1, off offset:" off " sc0 sc1" \
                                 : "=v"(hf[i]) : "v"(hb) : "memory")
                LDH(0,"0");    LDH(1,"64");   LDH(2,"128");  LDH(3,"192");
                LDH(4,"256");  LDH(5,"320");  LDH(6,"384");  LDH(7,"448");
                LDH(8,"512");  LDH(9,"576");  LDH(10,"640"); LDH(11,"704");
                LDH(12,"768"); LDH(13,"832"); LDH(14,"896"); LDH(15,"960");
                asm volatile("s_waitcnt vmcnt(0)" ::: "memory");
                __builtin_amdgcn_sched_barrier(0);
                unsigned st = 0;
                #pragma unroll
                for (int p = 0; p < 16; ++p)
                    #pragma unroll
                    for (int d = 0; d < 4; ++d)
                        st |= (hf[p][d] & 0x40004000u) ^ expm;
                ok = !__any((int)(st != 0));
            }
            if (!ok) {
                // fallback: cheap sentinel wait, then bounded resweeps
                {
                    const unsigned int* fp = flags + (cluster + (l & 31)) * 16;
                    int n = 0;
                    bool fok;
                    do {
                        unsigned v = __hip_atomic_load(fp, __ATOMIC_RELAXED,
                                                       __HIP_MEMORY_SCOPE_AGENT);
                        fok = __all((int)(v >= (unsigned)t));
                    } while (!fok && ++n < 100000);
                }
                int n = 0;
                do {
                    LDH(0,"0");    LDH(1,"64");   LDH(2,"128");  LDH(3,"192");
                    LDH(4,"256");  LDH(5,"320");  LDH(6,"384");  LDH(7,"448");
                    LDH(8,"512");  LDH(9,"576");  LDH(10,"640"); LDH(11,"704");
                    LDH(12,"768"); LDH(13,"832"); LDH(14,"896"); LDH(15,"960");
                    asm volatile("s_waitcnt vmcnt(0)" ::: "memory");
                    __builtin_amdgcn_sched_barrier(0);
                    unsigned st = 0;
                    #pragma unroll
                    for (int p = 0; p < 16; ++p)
                        #pragma unroll
                        for (int d = 0; d < 4; ++d)
                            st |= (hf[p][d] & 0x40004000u) ^ expm;
                    ok = !__any((int)(st != 0));
                } while (!ok && ++n < 2000);
#undef LDH
            }
            // strip tags -> clean f16 A-fragments
            #pragma unroll
            for (int p = 0; p < 16; ++p) {
                #pragma unroll
                for (int d = 0; d < 4; ++d) hf[p][d] &= 0xBFFFBFFFu;
            }
            __builtin_amdgcn_sched_barrier(0);
            #pragma unroll
            for (int ks = 0; ks < 16; ++ks) {
                f16x8 a = __builtin_bit_cast(f16x8, hf[ks]);
                const char* ub = uLds + (size_t)((ks*4 + lk)*UCOLS + c*16 + l15) * 16;
                f16x8 bz = *(const f16x8*)(ub);
                f16x8 br = *(const f16x8*)(ub + 512);    // +32 cols
                f16x8 bh = *(const f16x8*)(ub + 1024);   // +64 cols
                az = __builtin_amdgcn_mfma_f32_16x16x32_f16(a, bz, az, 0, 0, 0);
                ar = __builtin_amdgcn_mfma_f32_16x16x32_f16(a, br, ar, 0, 0, 0);
                ah = __builtin_amdgcn_mfma_f32_16x16x32_f16(a, bh, ah, 0, 0, 0);
            }
        }
        // gates
        #pragma unroll
        for (int i = 0; i < 4; ++i) {
            int row = b0 + i;
            float z  = 1.f / (1.f + __expf(-((float)xz4[i] + az[i] + b1z)));
            float rg = 1.f / (1.f + __expf(-((float)xr4[i] + ar[i] + b1r)));
            float ag = (float)xh4[i] + rg * (ah[i] + b1h);
            float hc = 1.f - 2.f / (__expf(2.f * ag) + 1.f);
            float hn = z * hold[i] + (1.f - z) * hc;
            if (!((mbv >> row) & 1ull)) hn = hold[i];
            hold[i] = hn;
        }
        if (t < SS - 1) {
            const unsigned tg = (((unsigned)(t + 1) >> 1) & 1u) << 14;
            // tag + stage into wave-private LDS tile [16 rows][16 cols]
            #pragma unroll
            for (int i = 0; i < 4; ++i) {
                unsigned hb16 = (unsigned)__builtin_bit_cast(unsigned short, (_Float16)hold[i]);
                if ((hb16 & 0x7FFFu) >= 0x3C00u) hb16 = (hb16 & 0x8000u) | 0x3BFFu;
                scr[(lk*4 + i)*16 + l15] = (unsigned short)(hb16 | tg);
            }
            // intra-wave transpose read (lockstep; compiler inserts lgkmcnt)
            u32x2 pk = *(const u32x2*)(scr + (l >> 2)*16 + (l & 3)*4);
            char* hnxt = hpub + (size_t)((t + 1) & 1) * HBYTES;
            unsigned long long pa = (unsigned long long)
                (hnxt + (size_t)(rb + (l >> 2))*1024 + (size_t)(s*SCOLS + c*16 + (l & 3)*4)*2);
            asm volatile("global_store_dwordx2 %0, %1, off sc0 sc1"
                         :: "v"(pa), "v"(pk) : "memory");
            // fire-and-forget sentinel (tags cover reordering)
            if (l == 0)
                __hip_atomic_store(flags + (cluster + (s*2 + c)) * 16,
                                   (unsigned)(t + 1),
                                   __ATOMIC_RELAXED, __HIP_MEMORY_SCOPE_AGENT);
        } else {
            #pragma unroll
            for (int i = 0; i < 4; ++i)
                hlast[(b0 + i)*HH + j] = hold[i];
        }
    };

    for (int t = 0; t < SS; t += 2) {
        step(t, xpe0, xpe1, xpe2, mbe);
        {   // prefetch even slot <- t+2
            int tl = (t + 2 < SS) ? t + 2 : SS - 1;
            const _Float16* xt = xp + (size_t)tl * H3 * BB;
            xpe0 = *(const f16x4*)(xt + (0*HH + j)*BB + b0);
            xpe1 = *(const f16x4*)(xt + (1*HH + j)*BB + b0);
            xpe2 = *(const f16x4*)(xt + (2*HH + j)*BB + b0);
            mbe = maskbits[tl];
        }
        step(t + 1, xpo0, xpo1, xpo2, mbo);
        {   // prefetch odd slot <- t+3
            int tl = (t + 3 < SS) ? t + 3 : SS - 1;
            const _Float16* xt = xp + (size_t)tl * H3 * BB;
            xpo0 = *(const f16x4*)(xt + (0*HH + j)*BB + b0);
            xpo1 = *(const f16x4*)(xt + (1*HH + j)*BB + b0);
            xpo2 = *(const f16x4*)(xt + (2*HH + j)*BB + b0);
            mbo = maskbits[tl];
        }
    }
}

// ---------------------------------------------------------------------------
// K3a: logits + per-WG softmax partials
// ---------------------------------------------------------------------------
__global__ __launch_bounds__(256) void k3_logits(
    const float* __restrict__ hin, const float* __restrict__ Wd,
    const float* __restrict__ bd, float* __restrict__ out,
    float* __restrict__ partials)
{
    const int nt = blockIdx.x;
    const int tid = threadIdx.x;
    __shared__ _Float16 hLds[64 * 512];

    for (int c = tid; c < 64 * 64; c += 256) {
        int row = c >> 6, kc = c & 63;
        const float* src = hin + row * HH + kc * 8;
        float4 f0 = *(const float4*)(src);
        float4 f1 = *(const float4*)(src + 4);
        f16x8 v;
        v[0]=(_Float16)f0.x; v[1]=(_Float16)f0.y; v[2]=(_Float16)f0.z; v[3]=(_Float16)f0.w;
        v[4]=(_Float16)f1.x; v[5]=(_Float16)f1.y; v[6]=(_Float16)f1.z; v[7]=(_Float16)f1.w;
        int byte = row * 1024 + ((kc * 16) ^ ((row & 7) << 4));
        *(f16x8*)((char*)hLds + byte) = v;
    }
    __syncthreads();

    const int w = tid >> 6, l = tid & 63;
    const int l15 = l & 15, lk = l >> 4;
    f32x4 acc[8] = {};

    for (int ks = 0; ks < 16; ++ks) {
        int arow = 16 * w + l15;
        int abyte = arow * 1024 + ((((ks * 32 + lk * 8) * 2)) ^ ((arow & 7) << 4));
        f16x8 aFrag = *(const f16x8*)((const char*)hLds + abyte);
        int krow = ks * 32 + lk * 8;
        #pragma unroll
        for (int ns = 0; ns < 8; ++ns) {
            int col = nt * 128 + ns * 16 + l15;
            f16x8 bFrag;
            if (col < VV) {
                #pragma unroll
                for (int i = 0; i < 8; ++i) bFrag[i] = (_Float16)Wd[(size_t)(krow + i) * VV + col];
            } else {
                #pragma unroll
                for (int i = 0; i < 8; ++i) bFrag[i] = (_Float16)0.f;
            }
            acc[ns] = __builtin_amdgcn_mfma_f32_16x16x32_f16(aFrag, bFrag, acc[ns], 0, 0, 0);
        }
    }

    float lg[8][4];
    float m[4] = {-3.4e38f, -3.4e38f, -3.4e38f, -3.4e38f};
    float ss[4] = {0.f, 0.f, 0.f, 0.f};
    #pragma unroll
    for (int ns = 0; ns < 8; ++ns) {
        int col = nt * 128 + ns * 16 + l15;
        bool ok = col < VV;
        float bv = ok ? bd[col] : 0.f;
        #pragma unroll
        for (int i = 0; i < 4; ++i) {
            int row = 16 * w + lk * 4 + i;
            float v = acc[ns][i] + bv;
            lg[ns][i] = ok ? v : -3.4e38f;
            if (ok) {
                out[(size_t)row * VV + col] = v;
                m[i] = fmaxf(m[i], v);
            }
        }
    }
    #pragma unroll
    for (int i = 0; i < 4; ++i) {
        #pragma unroll
        for (int ns = 0; ns < 8; ++ns)
            if (lg[ns][i] > -3.3e38f) ss[i] += __expf(lg[ns][i] - m[i]);
        for (int d = 1; d < 16; d <<= 1) {
            float m2 = __shfl_xor(m[i], d);
            float s2 = __shfl_xor(ss[i], d);
            float nM = fmaxf(m[i], m2);
            ss[i] = ss[i] * __expf(m[i] - nM) + s2 * __expf(m2 - nM);
            m[i] = nM;
        }
        if (l15 == 0) {
            int row = 16 * w + lk * 4 + i;
            partials[((size_t)nt * 64 + row) * 2 + 0] = m[i];
            partials[((size_t)nt * 64 + row) * 2 + 1] = ss[i];
        }
    }
}

__global__ __launch_bounds__(64) void k3_reduce(
    const float* __restrict__ partials, float* __restrict__ rowMS)
{
    int row = blockIdx.x, l = threadIdx.x;
    float M = -3.4e38f, Ssum = 0.f;
    for (int p = l; p < 393; p += 64) {
        float mp = partials[((size_t)p * 64 + row) * 2 + 0];
        float sp = partials[((size_t)p * 64 + row) * 2 + 1];
        float nM = fmaxf(M, mp);
        Ssum = Ssum * __expf(M - nM) + sp * __expf(mp - nM);
        M = nM;
    }
    for (int d = 1; d < 64; d <<= 1) {
        float m2 = __shfl_xor(M, d), s2 = __shfl_xor(Ssum, d);
        float nM = fmaxf(M, m2);
        Ssum = Ssum * __expf(M - nM) + s2 * __expf(m2 - nM);
        M = nM;
    }
    if (l == 0) { rowMS[row * 2] = M; rowMS[row * 2 + 1] = Ssum; }
}

__global__ __launch_bounds__(256) void k3_softmax(
    float* __restrict__ out, const float* __restrict__ rowMS)
{
    int col = blockIdx.x * 256 + threadIdx.x;
    int row = blockIdx.y;
    if (col < VV) {
        float M = rowMS[row * 2], Sv = rowMS[row * 2 + 1];
        size_t idx = (size_t)row * VV + col;
        out[idx] = __expf(out[idx] - M) / Sv;
    }
}

// ---------------------------------------------------------------------------
extern "C" void kernel_launch(void* const* d_in, const int* in_sizes, int n_in,
                              void* d_out, int out_size, void* d_ws, size_t ws_size,
                              hipStream_t stream) {
    const int*   tokens = (const int*)  d_in[0];
    const float* emb    = (const float*)d_in[1];
    const float* W      = (const float*)d_in[2];
    const float* U      = (const float*)d_in[3];
    const float* bias   = (const float*)d_in[4];
    const float* Wd     = (const float*)d_in[5];
    const float* bd     = (const float*)d_in[6];
    float* out = (float*)d_out;

    const size_t XP_BYTES   = (size_t)SS * BB * H3 * 2;     // 100,663,296
    const size_t WSU_BYTES  = (size_t)NSL * UBYTES;         // 1,572,864
    const size_t WSW_BYTES  = (size_t)32 * H3 * 8 * 2;      // 786,432
    const size_t HPUB_BYTES = 2 * (size_t)HBYTES;           // 131,072
    const size_t HLAST_BYTES= (size_t)BB * HH * 4;          // 131,072
    const size_t MASK_BYTES = (size_t)SS * 8;               // 4,096
    const size_t FLAG_BYTES = 8192;                         // 128 flags x 64B
    const size_t PART_BYTES = (size_t)393 * 64 * 2 * 4;     // 201,216

    char* ws = (char*)d_ws;
    _Float16* xp    = (_Float16*)ws;
    _Float16* wsU   = (_Float16*)(ws + XP_BYTES);
    _Float16* wsW   = (_Float16*)(ws + XP_BYTES + WSU_BYTES);
    char*     hpub  =            ws + XP_BYTES + WSU_BYTES + WSW_BYTES;
    float*    hlast = (float*)  (hpub + HPUB_BYTES);
    unsigned long long* maskb = (unsigned long long*)(hpub + HPUB_BYTES + HLAST_BYTES);
    unsigned int* flags = (unsigned int*)(hpub + HPUB_BYTES + HLAST_BYTES + MASK_BYTES);
    float* partials = (float*)(hpub + HPUB_BYTES + HLAST_BYTES + MASK_BYTES + FLAG_BYTES);
    float* rowMS    = (float*)(hpub + HPUB_BYTES + HLAST_BYTES + MASK_BYTES + FLAG_BYTES + PART_BYTES);

    hipFuncSetAttribute((const void*)k2_scan,
                        hipFuncAttributeMaxDynamicSharedMemorySize, UBYTES + SCRB);

    // tag-safe init: buf0 first expects tag1 -> init bit14=0 (0x00);
    //                buf1 first expects tag0 -> init bit14=1 (0x40)
    hipMemsetAsync(hpub, 0x00, HBYTES, stream);
    hipMemsetAsync(hpub + HBYTES, 0x40, HBYTES, stream);
    hipMemsetAsync(flags, 0, FLAG_BYTES, stream);

    kPackW<<<32 * H3 / 256, 256, 0, stream>>>(W, wsW);
    kPackU<<<NSL, 256, 0, stream>>>(U, wsU);
    kMask<<<2, 256, 0, stream>>>(tokens, maskb);
    k1_embed_proj<<<dim3(12, 512), 256, 0, stream>>>(tokens, emb, wsW, bias, xp);

    k2_scan<<<NWG, 256, UBYTES + SCRB, stream>>>(xp, wsU, bias, maskb, hpub, hlast, flags);

    k3_logits<<<393, 256, 0, stream>>>(hlast, Wd, bd, out, partials);
    k3_reduce<<<64, 64, 0, stream>>>(partials, rowMS);
    k3_softmax<<<dim3((VV + 255) / 256, BB), 256, 0, stream>>>(out, rowMS);
}

// Round 14
// 3110.290 us; speedup vs baseline: 1.0606x; 1.0606x over previous
//
#include <hip/hip_runtime.h>
#include <hip/hip_bf16.h>

#define VV 50257
#define DD 256
#define HH 512
#define BB 64
#define SS 512
#define H3 1536
#define NWG 32          // 2 batch-groups x 16 hidden-slices
#define NSL 16          // slices
#define SCOLS 32        // hidden cols per slice
#define UCOLS 96        // 3 gates x 32
#define UBYTES (64*UCOLS*16)   // 98304 B resident U slice image
#define SCRB 2048              // 4 waves x 512 B transpose scratch
#define HBYTES (BB*HH*2)       // 65536 B f16 h image [64][512]

typedef _Float16 f16x8 __attribute__((ext_vector_type(8)));
typedef _Float16 f16x4 __attribute__((ext_vector_type(4)));
typedef float f32x4 __attribute__((ext_vector_type(4)));
typedef unsigned int u32x4 __attribute__((ext_vector_type(4)));
typedef unsigned int u32x2 __attribute__((ext_vector_type(2)));

#define AS1 __attribute__((address_space(1)))
#define AS3 __attribute__((address_space(3)))
#define GLL16(g, s) __builtin_amdgcn_global_load_lds((const AS1 char*)(g), (AS3 char*)(s), 16, 0, 0)

// ---------------------------------------------------------------------------
// Pack W (f32 [256][1536]) -> f16 k-major
// ---------------------------------------------------------------------------
__global__ __launch_bounds__(256) void kPackW(const float* __restrict__ W,
                                              _Float16* __restrict__ wsW) {
    int idx = blockIdx.x * 256 + threadIdx.x;
    int kb = idx / H3, col = idx % H3;
    f16x8 v;
    #pragma unroll
    for (int e = 0; e < 8; ++e) v[e] = (_Float16)W[(size_t)(kb*8+e)*H3 + col];
    *(f16x8*)(wsW + (size_t)idx*8) = v;
}

// ---------------------------------------------------------------------------
// Pack U -> per-slice k-major images. Slice s: packed col pc = gi*32 + cl
// <- source col gi*512 + s*32 + cl.  Row kb: 96 cols x 16B.
// ---------------------------------------------------------------------------
__global__ __launch_bounds__(256) void kPackU(const float* __restrict__ U,
                                              _Float16* __restrict__ wsU) {
    int s = blockIdx.x;                            // 16 slices
    for (int idx = threadIdx.x; idx < 64*UCOLS; idx += 256) {
        int kb = idx / UCOLS, pc = idx % UCOLS;
        int gi = pc / SCOLS, cl = pc % SCOLS;
        int gcol = gi*HH + s*SCOLS + cl;
        f16x8 v;
        #pragma unroll
        for (int e = 0; e < 8; ++e) v[e] = (_Float16)U[(size_t)(kb*8+e)*H3 + gcol];
        *(f16x8*)(wsU + (size_t)s*(UBYTES/2) + (size_t)idx*8) = v;
    }
}

// maskbits[t] bit r = (tokens[r][t] != 0)
__global__ __launch_bounds__(256) void kMask(const int* __restrict__ tokens,
                                             unsigned long long* __restrict__ mb) {
    int t = blockIdx.x * 256 + threadIdx.x;
    if (t < SS) {
        unsigned long long m = 0ull;
        for (int r = 0; r < BB; ++r)
            m |= (unsigned long long)(tokens[r*SS + t] != 0) << r;
        mb[t] = m;
    }
}

// ---------------------------------------------------------------------------
// K1: xp[t][col][b] (f16) = (emb[tokens] @ W + b0)
// ---------------------------------------------------------------------------
__global__ __launch_bounds__(256) void k1_embed_proj(
    const int* __restrict__ tokens, const float* __restrict__ emb,
    const _Float16* __restrict__ wsW, const float* __restrict__ bias,
    _Float16* __restrict__ xp)
{
    const int s  = blockIdx.y;
    const int nt = blockIdx.x;
    const int tid = threadIdx.x;
    __shared__ _Float16 aLds[64 * 256];

    for (int c = tid; c < 64 * 32; c += 256) {
        int row = c >> 5, kc = c & 31;
        int tok = tokens[row * SS + s];
        const float* src = emb + (size_t)tok * DD + kc * 8;
        float4 f0 = *(const float4*)(src);
        float4 f1 = *(const float4*)(src + 4);
        f16x8 v;
        v[0]=(_Float16)f0.x; v[1]=(_Float16)f0.y; v[2]=(_Float16)f0.z; v[3]=(_Float16)f0.w;
        v[4]=(_Float16)f1.x; v[5]=(_Float16)f1.y; v[6]=(_Float16)f1.z; v[7]=(_Float16)f1.w;
        int byte = row * 512 + ((kc * 16) ^ ((row & 7) << 4));
        *(f16x8*)((char*)aLds + byte) = v;
    }
    __syncthreads();

    const int w = tid >> 6, l = tid & 63;
    const int l15 = l & 15, lk = l >> 4;
    const int colbase = nt * 128;
    f32x4 acc[8] = {};

    for (int ks = 0; ks < 8; ++ks) {
        int arow = 16 * w + l15;
        f16x8 aF = *(const f16x8*)((const char*)aLds + arow*512 + (((ks*32 + lk*8)*2) ^ ((arow & 7) << 4)));
        int kb = ks*4 + lk;
        #pragma unroll
        for (int ns = 0; ns < 8; ++ns) {
            int col = colbase + ns * 16 + l15;
            f16x8 bF = *(const f16x8*)(wsW + ((size_t)kb * H3 + col) * 8);
            acc[ns] = __builtin_amdgcn_mfma_f32_16x16x32_f16(aF, bF, acc[ns], 0, 0, 0);
        }
    }
    #pragma unroll
    for (int ns = 0; ns < 8; ++ns) {
        int col = colbase + ns * 16 + l15;
        float b0 = bias[col];
        f16x4 vv;
        #pragma unroll
        for (int i = 0; i < 4; ++i) vv[i] = (_Float16)(acc[ns][i] + b0);
        *(f16x4*)(xp + ((size_t)s * H3 + col) * BB + 16*w + lk*4) = vv;
    }
}

// ---------------------------------------------------------------------------
// K2: persistent GRU scan — in-band parity tags + per-packet dataflow.
// 2 batch-groups x 16 slices; wave (mi,c) of WG (g,s) owns rows
// g*32+mi*16..+15, cols s*32+c*16..+15.  A-fragment packet p (k-cols
// 32p..32p+31) is produced entirely by slice p's two waves, whose sentinels
// are lanes 2p,2p+1 of the cluster flag ballot.  Per step: poll sentinels;
// for each NEWLY-ready packet, load it (tag-verified) and MFMA immediately —
// early slices' compute overlaps the wait for the last producer.  Publish =
// tagged dwordx2 via wave-local LDS transpose, then own sentinel.
// No barriers, no vmcnt on the publish side.
// ---------------------------------------------------------------------------
__global__ __launch_bounds__(256) void k2_scan(
    const _Float16* __restrict__ xp, const _Float16* __restrict__ wsU,
    const float* __restrict__ bias, const unsigned long long* __restrict__ maskbits,
    char* __restrict__ hpub, float* __restrict__ hlast,
    unsigned int* __restrict__ flags)
{
    extern __shared__ char uLds[];
    const int tid = threadIdx.x;
    const int g = blockIdx.x >> 4;              // batch group (0..1)
    const int s = blockIdx.x & 15;              // hidden slice (0..15)
    const int w = tid >> 6, l = tid & 63;
    const int l15 = l & 15, lk = l >> 4;
    const int mi = w >> 1, c = w & 1;
    const int rb = g*32 + mi*16;                // wave's row band
    const int j  = s*SCOLS + c*16 + l15;        // this thread's hidden col
    const int b0 = rb + lk*4;
    const int cluster = (g*2 + mi) << 5;        // 32 producer waves per cluster
    unsigned short* scr = (unsigned short*)(uLds + UBYTES + w*512);

    // stage resident U slice (24 x 4KB)
    {
        const char* src = (const char*)wsU + (size_t)s * UBYTES;
        #pragma unroll
        for (int base = 0; base < UBYTES; base += 4096)
            GLL16(src + base + tid*16, uLds + base + tid*16);
    }

    // prologue prefetch: xp(0) -> even slot, xp(1) -> odd slot
    f16x4 xpe0, xpe1, xpe2, xpo0, xpo1, xpo2;
    unsigned long long mbe, mbo;
    {
        const _Float16* x0 = xp;
        xpe0 = *(const f16x4*)(x0 + (0*HH + j)*BB + b0);
        xpe1 = *(const f16x4*)(x0 + (1*HH + j)*BB + b0);
        xpe2 = *(const f16x4*)(x0 + (2*HH + j)*BB + b0);
        const _Float16* x1 = xp + (size_t)H3 * BB;
        xpo0 = *(const f16x4*)(x1 + (0*HH + j)*BB + b0);
        xpo1 = *(const f16x4*)(x1 + (1*HH + j)*BB + b0);
        xpo2 = *(const f16x4*)(x1 + (2*HH + j)*BB + b0);
        mbe = maskbits[0];
        mbo = maskbits[1];
    }
    const float b1z = bias[H3 + j];
    const float b1r = bias[H3 + HH + j];
    const float b1h = bias[H3 + 2*HH + j];
    float hold[4] = {};
    __syncthreads();   // U staged (only barrier in kernel)

    auto step = [&](int t, f16x4 xz4, f16x4 xr4, f16x4 xh4,
                    unsigned long long mbv) __attribute__((always_inline)) {
        f32x4 az = {}, ar = {}, ah = {};
        if (t > 0) {
            const unsigned expm = ((t >> 1) & 1) ? 0x40004000u : 0u;
            const char* hsrc = hpub + (size_t)(t & 1) * HBYTES;
            unsigned long long hb = (unsigned long long)(hsrc + (rb + l15)*1024 + lk*16);
            u32x4 hf[16];
            const unsigned int* fp = flags + (cluster + (l & 31)) * 16;
            unsigned done = 0;
            int n = 0;

#define LDH(i, off) asm volatile("global_load_dwordx4 %0, %1, off offset:" off " sc0 sc1" \
                                 : "=v"(hf[i]) : "v"(hb) : "memory")
#define VMF(p, uboff)                                                          \
            if (newly & (1u << (p))) {                                         \
                unsigned st = 0;                                               \
                for (int d = 0; d < 4; ++d)                                    \
                    st |= (hf[p][d] & 0x40004000u) ^ expm;                     \
                if (!__any((int)(st != 0))) {                                  \
                    for (int d = 0; d < 4; ++d) hf[p][d] &= 0xBFFFBFFFu;       \
                    f16x8 a = __builtin_bit_cast(f16x8, hf[p]);                \
                    const char* ub = uLds + (size_t)(uboff) + c*256 + l15*16;  \
                    az = __builtin_amdgcn_mfma_f32_16x16x32_f16(a, *(const f16x8*)(ub), az, 0, 0, 0);          \
                    ar = __builtin_amdgcn_mfma_f32_16x16x32_f16(a, *(const f16x8*)(ub + 512), ar, 0, 0, 0);    \
                    ah = __builtin_amdgcn_mfma_f32_16x16x32_f16(a, *(const f16x8*)(ub + 1024), ah, 0, 0, 0);   \
                    done |= 1u << (p);                                         \
                }                                                              \
            }

            while (done != 0xFFFFu && n < 100000) {
                unsigned v = __hip_atomic_load(fp, __ATOMIC_RELAXED,
                                               __HIP_MEMORY_SCOPE_AGENT);
                unsigned long long bal = __ballot((int)(v >= (unsigned)t));
                unsigned b32 = (unsigned)bal;
                unsigned pairs = b32 & (b32 >> 1) & 0x55555555u;
                unsigned rm = 0;
                #pragma unroll
                for (int p = 0; p < 16; ++p) rm |= ((pairs >> (2*p)) & 1u) << p;
                unsigned newly = (rm & ~done) | (done ^ done); // wave-uniform
                newly = rm & ~done;
                if (newly) {
                    if (newly & 1u<<0)  LDH(0,"0");
                    if (newly & 1u<<1)  LDH(1,"64");
                    if (newly & 1u<<2)  LDH(2,"128");
                    if (newly & 1u<<3)  LDH(3,"192");
                    if (newly & 1u<<4)  LDH(4,"256");
                    if (newly & 1u<<5)  LDH(5,"320");
                    if (newly & 1u<<6)  LDH(6,"384");
                    if (newly & 1u<<7)  LDH(7,"448");
                    if (newly & 1u<<8)  LDH(8,"512");
                    if (newly & 1u<<9)  LDH(9,"576");
                    if (newly & 1u<<10) LDH(10,"640");
                    if (newly & 1u<<11) LDH(11,"704");
                    if (newly & 1u<<12) LDH(12,"768");
                    if (newly & 1u<<13) LDH(13,"832");
                    if (newly & 1u<<14) LDH(14,"896");
                    if (newly & 1u<<15) LDH(15,"960");
                    asm volatile("s_waitcnt vmcnt(0)" ::: "memory");
                    __builtin_amdgcn_sched_barrier(0);
                    VMF(0,  (0*4 + lk)*UCOLS*16)
                    VMF(1,  (1*4 + lk)*UCOLS*16)
                    VMF(2,  (2*4 + lk)*UCOLS*16)
                    VMF(3,  (3*4 + lk)*UCOLS*16)
                    VMF(4,  (4*4 + lk)*UCOLS*16)
                    VMF(5,  (5*4 + lk)*UCOLS*16)
                    VMF(6,  (6*4 + lk)*UCOLS*16)
                    VMF(7,  (7*4 + lk)*UCOLS*16)
                    VMF(8,  (8*4 + lk)*UCOLS*16)
                    VMF(9,  (9*4 + lk)*UCOLS*16)
                    VMF(10, (10*4 + lk)*UCOLS*16)
                    VMF(11, (11*4 + lk)*UCOLS*16)
                    VMF(12, (12*4 + lk)*UCOLS*16)
                    VMF(13, (13*4 + lk)*UCOLS*16)
                    VMF(14, (14*4 + lk)*UCOLS*16)
                    VMF(15, (15*4 + lk)*UCOLS*16)
                }
                ++n;
            }
#undef VMF
#undef LDH
        }
        // gates
        #pragma unroll
        for (int i = 0; i < 4; ++i) {
            int row = b0 + i;
            float z  = 1.f / (1.f + __expf(-((float)xz4[i] + az[i] + b1z)));
            float rg = 1.f / (1.f + __expf(-((float)xr4[i] + ar[i] + b1r)));
            float ag = (float)xh4[i] + rg * (ah[i] + b1h);
            float hc = 1.f - 2.f / (__expf(2.f * ag) + 1.f);
            float hn = z * hold[i] + (1.f - z) * hc;
            if (!((mbv >> row) & 1ull)) hn = hold[i];
            hold[i] = hn;
        }
        if (t < SS - 1) {
            const unsigned tg = (((unsigned)(t + 1) >> 1) & 1u) << 14;
            // tag + stage into wave-private LDS tile [16 rows][16 cols]
            #pragma unroll
            for (int i = 0; i < 4; ++i) {
                unsigned hb16 = (unsigned)__builtin_bit_cast(unsigned short, (_Float16)hold[i]);
                if ((hb16 & 0x7FFFu) >= 0x3C00u) hb16 = (hb16 & 0x8000u) | 0x3BFFu;
                scr[(lk*4 + i)*16 + l15] = (unsigned short)(hb16 | tg);
            }
            // intra-wave transpose read (lockstep; compiler inserts lgkmcnt)
            u32x2 pk = *(const u32x2*)(scr + (l >> 2)*16 + (l & 3)*4);
            char* hnxt = hpub + (size_t)((t + 1) & 1) * HBYTES;
            unsigned long long pa = (unsigned long long)
                (hnxt + (size_t)(rb + (l >> 2))*1024 + (size_t)(s*SCOLS + c*16 + (l & 3)*4)*2);
            asm volatile("global_store_dwordx2 %0, %1, off sc0 sc1"
                         :: "v"(pa), "v"(pk) : "memory");
            // fire-and-forget sentinel (tags cover reordering)
            if (l == 0)
                __hip_atomic_store(flags + (cluster + (s*2 + c)) * 16,
                                   (unsigned)(t + 1),
                                   __ATOMIC_RELAXED, __HIP_MEMORY_SCOPE_AGENT);
        } else {
            #pragma unroll
            for (int i = 0; i < 4; ++i)
                hlast[(b0 + i)*HH + j] = hold[i];
        }
    };

    for (int t = 0; t < SS; t += 2) {
        step(t, xpe0, xpe1, xpe2, mbe);
        {   // prefetch even slot <- t+2
            int tl = (t + 2 < SS) ? t + 2 : SS - 1;
            const _Float16* xt = xp + (size_t)tl * H3 * BB;
            xpe0 = *(const f16x4*)(xt + (0*HH + j)*BB + b0);
            xpe1 = *(const f16x4*)(xt + (1*HH + j)*BB + b0);
            xpe2 = *(const f16x4*)(xt + (2*HH + j)*BB + b0);
            mbe = maskbits[tl];
        }
        step(t + 1, xpo0, xpo1, xpo2, mbo);
        {   // prefetch odd slot <- t+3
            int tl = (t + 3 < SS) ? t + 3 : SS - 1;
            const _Float16* xt = xp + (size_t)tl * H3 * BB;
            xpo0 = *(const f16x4*)(xt + (0*HH + j)*BB + b0);
            xpo1 = *(const f16x4*)(xt + (1*HH + j)*BB + b0);
            xpo2 = *(const f16x4*)(xt + (2*HH + j)*BB + b0);
            mbo = maskbits[tl];
        }
    }
}

// ---------------------------------------------------------------------------
// K3a: logits + per-WG softmax partials
// ---------------------------------------------------------------------------
__global__ __launch_bounds__(256) void k3_logits(
    const float* __restrict__ hin, const float* __restrict__ Wd,
    const float* __restrict__ bd, float* __restrict__ out,
    float* __restrict__ partials)
{
    const int nt = blockIdx.x;
    const int tid = threadIdx.x;
    __shared__ _Float16 hLds[64 * 512];

    for (int c = tid; c < 64 * 64; c += 256) {
        int row = c >> 6, kc = c & 63;
        const float* src = hin + row * HH + kc * 8;
        float4 f0 = *(const float4*)(src);
        float4 f1 = *(const float4*)(src + 4);
        f16x8 v;
        v[0]=(_Float16)f0.x; v[1]=(_Float16)f0.y; v[2]=(_Float16)f0.z; v[3]=(_Float16)f0.w;
        v[4]=(_Float16)f1.x; v[5]=(_Float16)f1.y; v[6]=(_Float16)f1.z; v[7]=(_Float16)f1.w;
        int byte = row * 1024 + ((kc * 16) ^ ((row & 7) << 4));
        *(f16x8*)((char*)hLds + byte) = v;
    }
    __syncthreads();

    const int w = tid >> 6, l = tid & 63;
    const int l15 = l & 15, lk = l >> 4;
    f32x4 acc[8] = {};

    for (int ks = 0; ks < 16; ++ks) {
        int arow = 16 * w + l15;
        int abyte = arow * 1024 + ((((ks * 32 + lk * 8) * 2)) ^ ((arow & 7) << 4));
        f16x8 aFrag = *(const f16x8*)((const char*)hLds + abyte);
        int krow = ks * 32 + lk * 8;
        #pragma unroll
        for (int ns = 0; ns < 8; ++ns) {
            int col = nt * 128 + ns * 16 + l15;
            f16x8 bFrag;
            if (col < VV) {
                #pragma unroll
                for (int i = 0; i < 8; ++i) bFrag[i] = (_Float16)Wd[(size_t)(krow + i) * VV + col];
            } else {
                #pragma unroll
                for (int i = 0; i < 8; ++i) bFrag[i] = (_Float16)0.f;
            }
            acc[ns] = __builtin_amdgcn_mfma_f32_16x16x32_f16(aFrag, bFrag, acc[ns], 0, 0, 0);
        }
    }

    float lg[8][4];
    float m[4] = {-3.4e38f, -3.4e38f, -3.4e38f, -3.4e38f};
    float ss[4] = {0.f, 0.f, 0.f, 0.f};
    #pragma unroll
    for (int ns = 0; ns < 8; ++ns) {
        int col = nt * 128 + ns * 16 + l15;
        bool ok = col < VV;
        float bv = ok ? bd[col] : 0.f;
        #pragma unroll
        for (int i = 0; i < 4; ++i) {
            int row = 16 * w + lk * 4 + i;
            float v = acc[ns][i] + bv;
            lg[ns][i] = ok ? v : -3.4e38f;
            if (ok) {
                out[(size_t)row * VV + col] = v;
                m[i] = fmaxf(m[i], v);
            }
        }
    }
    #pragma unroll
    for (int i = 0; i < 4; ++i) {
        #pragma unroll
        for (int ns = 0; ns < 8; ++ns)
            if (lg[ns][i] > -3.3e38f) ss[i] += __expf(lg[ns][i] - m[i]);
        for (int d = 1; d < 16; d <<= 1) {
            float m2 = __shfl_xor(m[i], d);
            float s2 = __shfl_xor(ss[i], d);
            float nM = fmaxf(m[i], m2);
            ss[i] = ss[i] * __expf(m[i] - nM) + s2 * __expf(m2 - nM);
            m[i] = nM;
        }
        if (l15 == 0) {
            int row = 16 * w + lk * 4 + i;
            partials[((size_t)nt * 64 + row) * 2 + 0] = m[i];
            partials[((size_t)nt * 64 + row) * 2 + 1] = ss[i];
        }
    }
}

__global__ __launch_bounds__(64) void k3_reduce(
    const float* __restrict__ partials, float* __restrict__ rowMS)
{
    int row = blockIdx.x, l = threadIdx.x;
    float M = -3.4e38f, Ssum = 0.f;
    for (int p = l; p < 393; p += 64) {
        float mp = partials[((size_t)p * 64 + row) * 2 + 0];
        float sp = partials[((size_t)p * 64 + row) * 2 + 1];
        float nM = fmaxf(M, mp);
        Ssum = Ssum * __expf(M - nM) + sp * __expf(mp - nM);
        M = nM;
    }
    for (int d = 1; d < 64; d <<= 1) {
        float m2 = __shfl_xor(M, d), s2 = __shfl_xor(Ssum, d);
        float nM = fmaxf(M, m2);
        Ssum = Ssum * __expf(M - nM) + s2 * __expf(m2 - nM);
        M = nM;
    }
    if (l == 0) { rowMS[row * 2] = M; rowMS[row * 2 + 1] = Ssum; }
}

__global__ __launch_bounds__(256) void k3_softmax(
    float* __restrict__ out, const float* __restrict__ rowMS)
{
    int col = blockIdx.x * 256 + threadIdx.x;
    int row = blockIdx.y;
    if (col < VV) {
        float M = rowMS[row * 2], Sv = rowMS[row * 2 + 1];
        size_t idx = (size_t)row * VV + col;
        out[idx] = __expf(out[idx] - M) / Sv;
    }
}

// ---------------------------------------------------------------------------
extern "C" void kernel_launch(void* const* d_in, const int* in_sizes, int n_in,
                              void* d_out, int out_size, void* d_ws, size_t ws_size,
                              hipStream_t stream) {
    const int*   tokens = (const int*)  d_in[0];
    const float* emb    = (const float*)d_in[1];
    const float* W      = (const float*)d_in[2];
    const float* U      = (const float*)d_in[3];
    const float* bias   = (const float*)d_in[4];
    const float* Wd     = (const float*)d_in[5];
    const float* bd     = (const float*)d_in[6];
    float* out = (float*)d_out;

    const size_t XP_BYTES   = (size_t)SS * BB * H3 * 2;     // 100,663,296
    const size_t WSU_BYTES  = (size_t)NSL * UBYTES;         // 1,572,864
    const size_t WSW_BYTES  = (size_t)32 * H3 * 8 * 2;      // 786,432
    const size_t HPUB_BYTES = 2 * (size_t)HBYTES;           // 131,072
    const size_t HLAST_BYTES= (size_t)BB * HH * 4;          // 131,072
    const size_t MASK_BYTES = (size_t)SS * 8;               // 4,096
    const size_t FLAG_BYTES = 8192;                         // 128 flags x 64B
    const size_t PART_BYTES = (size_t)393 * 64 * 2 * 4;     // 201,216

    char* ws = (char*)d_ws;
    _Float16* xp    = (_Float16*)ws;
    _Float16* wsU   = (_Float16*)(ws + XP_BYTES);
    _Float16* wsW   = (_Float16*)(ws + XP_BYTES + WSU_BYTES);
    char*     hpub  =            ws + XP_BYTES + WSU_BYTES + WSW_BYTES;
    float*    hlast = (float*)  (hpub + HPUB_BYTES);
    unsigned long long* maskb = (unsigned long long*)(hpub + HPUB_BYTES + HLAST_BYTES);
    unsigned int* flags = (unsigned int*)(hpub + HPUB_BYTES + HLAST_BYTES + MASK_BYTES);
    float* partials = (float*)(hpub + HPUB_BYTES + HLAST_BYTES + MASK_BYTES + FLAG_BYTES);
    float* rowMS    = (float*)(hpub + HPUB_BYTES + HLAST_BYTES + MASK_BYTES + FLAG_BYTES + PART_BYTES);

    hipFuncSetAttribute((const void*)k2_scan,
                        hipFuncAttributeMaxDynamicSharedMemorySize, UBYTES + SCRB);

    // tag-safe init: buf0 first expects tag1 -> init bit14=0 (0x00);
    //                buf1 first expects tag0 -> init bit14=1 (0x40)
    hipMemsetAsync(hpub, 0x00, HBYTES, stream);
    hipMemsetAsync(hpub + HBYTES, 0x40, HBYTES, stream);
    hipMemsetAsync(flags, 0, FLAG_BYTES, stream);

    kPackW<<<32 * H3 / 256, 256, 0, stream>>>(W, wsW);
    kPackU<<<NSL, 256, 0, stream>>>(U, wsU);
    kMask<<<2, 256, 0, stream>>>(tokens, maskb);
    k1_embed_proj<<<dim3(12, 512), 256, 0, stream>>>(tokens, emb, wsW, bias, xp);

    k2_scan<<<NWG, 256, UBYTES + SCRB, stream>>>(xp, wsU, bias, maskb, hpub, hlast, flags);

    k3_logits<<<393, 256, 0, stream>>>(hlast, Wd, bd, out, partials);
    k3_reduce<<<64, 64, 0, stream>>>(partials, rowMS);
    k3_softmax<<<dim3((VV + 255) / 256, BB), 256, 0, stream>>>(out, rowMS);
}

// Round 15
// 2511.101 us; speedup vs baseline: 1.3136x; 1.2386x over previous
//
#include <hip/hip_runtime.h>
#include <hip/hip_bf16.h>

#define VV 50257
#define DD 256
#define HH 512
#define BB 64
#define SS 512
#define H3 1536
#define NWG 32          // 2 batch-groups x 16 hidden-slices
#define NSL 16          // slices
#define SCOLS 32        // hidden cols per slice
#define UCOLS 96        // 3 gates x 32
#define UBYTES (64*UCOLS*16)   // 98304 B resident U slice image
#define SCRB 2048              // 4 waves x 512 B transpose scratch
#define HBYTES (BB*HH*2)       // 65536 B f16 h image [64][512]

typedef _Float16 f16x8 __attribute__((ext_vector_type(8)));
typedef _Float16 f16x4 __attribute__((ext_vector_type(4)));
typedef float f32x4 __attribute__((ext_vector_type(4)));
typedef unsigned int u32x4 __attribute__((ext_vector_type(4)));
typedef unsigned int u32x2 __attribute__((ext_vector_type(2)));

#define AS1 __attribute__((address_space(1)))
#define AS3 __attribute__((address_space(3)))
#define GLL16(g, s) __builtin_amdgcn_global_load_lds((const AS1 char*)(g), (AS3 char*)(s), 16, 0, 0)

// ---------------------------------------------------------------------------
// Pack W (f32 [256][1536]) -> f16 k-major
// ---------------------------------------------------------------------------
__global__ __launch_bounds__(256) void kPackW(const float* __restrict__ W,
                                              _Float16* __restrict__ wsW) {
    int idx = blockIdx.x * 256 + threadIdx.x;
    int kb = idx / H3, col = idx % H3;
    f16x8 v;
    #pragma unroll
    for (int e = 0; e < 8; ++e) v[e] = (_Float16)W[(size_t)(kb*8+e)*H3 + col];
    *(f16x8*)(wsW + (size_t)idx*8) = v;
}

// ---------------------------------------------------------------------------
// Pack U -> per-slice k-major images. Slice s: packed col pc = gi*32 + cl
// <- source col gi*512 + s*32 + cl.  Row kb: 96 cols x 16B.
// ---------------------------------------------------------------------------
__global__ __launch_bounds__(256) void kPackU(const float* __restrict__ U,
                                              _Float16* __restrict__ wsU) {
    int s = blockIdx.x;                            // 16 slices
    for (int idx = threadIdx.x; idx < 64*UCOLS; idx += 256) {
        int kb = idx / UCOLS, pc = idx % UCOLS;
        int gi = pc / SCOLS, cl = pc % SCOLS;
        int gcol = gi*HH + s*SCOLS + cl;
        f16x8 v;
        #pragma unroll
        for (int e = 0; e < 8; ++e) v[e] = (_Float16)U[(size_t)(kb*8+e)*H3 + gcol];
        *(f16x8*)(wsU + (size_t)s*(UBYTES/2) + (size_t)idx*8) = v;
    }
}

// maskbits[t] bit r = (tokens[r][t] != 0)
__global__ __launch_bounds__(256) void kMask(const int* __restrict__ tokens,
                                             unsigned long long* __restrict__ mb) {
    int t = blockIdx.x * 256 + threadIdx.x;
    if (t < SS) {
        unsigned long long m = 0ull;
        for (int r = 0; r < BB; ++r)
            m |= (unsigned long long)(tokens[r*SS + t] != 0) << r;
        mb[t] = m;
    }
}

// ---------------------------------------------------------------------------
// K1: xp[t][col][b] (f16) = (emb[tokens] @ W + b0)
// ---------------------------------------------------------------------------
__global__ __launch_bounds__(256) void k1_embed_proj(
    const int* __restrict__ tokens, const float* __restrict__ emb,
    const _Float16* __restrict__ wsW, const float* __restrict__ bias,
    _Float16* __restrict__ xp)
{
    const int s  = blockIdx.y;
    const int nt = blockIdx.x;
    const int tid = threadIdx.x;
    __shared__ _Float16 aLds[64 * 256];

    for (int c = tid; c < 64 * 32; c += 256) {
        int row = c >> 5, kc = c & 31;
        int tok = tokens[row * SS + s];
        const float* src = emb + (size_t)tok * DD + kc * 8;
        float4 f0 = *(const float4*)(src);
        float4 f1 = *(const float4*)(src + 4);
        f16x8 v;
        v[0]=(_Float16)f0.x; v[1]=(_Float16)f0.y; v[2]=(_Float16)f0.z; v[3]=(_Float16)f0.w;
        v[4]=(_Float16)f1.x; v[5]=(_Float16)f1.y; v[6]=(_Float16)f1.z; v[7]=(_Float16)f1.w;
        int byte = row * 512 + ((kc * 16) ^ ((row & 7) << 4));
        *(f16x8*)((char*)aLds + byte) = v;
    }
    __syncthreads();

    const int w = tid >> 6, l = tid & 63;
    const int l15 = l & 15, lk = l >> 4;
    const int colbase = nt * 128;
    f32x4 acc[8] = {};

    for (int ks = 0; ks < 8; ++ks) {
        int arow = 16 * w + l15;
        f16x8 aF = *(const f16x8*)((const char*)aLds + arow*512 + (((ks*32 + lk*8)*2) ^ ((arow & 7) << 4)));
        int kb = ks*4 + lk;
        #pragma unroll
        for (int ns = 0; ns < 8; ++ns) {
            int col = colbase + ns * 16 + l15;
            f16x8 bF = *(const f16x8*)(wsW + ((size_t)kb * H3 + col) * 8);
            acc[ns] = __builtin_amdgcn_mfma_f32_16x16x32_f16(aF, bF, acc[ns], 0, 0, 0);
        }
    }
    #pragma unroll
    for (int ns = 0; ns < 8; ++ns) {
        int col = colbase + ns * 16 + l15;
        float b0 = bias[col];
        f16x4 vv;
        #pragma unroll
        for (int i = 0; i < 4; ++i) vv[i] = (_Float16)(acc[ns][i] + b0);
        *(f16x4*)(xp + ((size_t)s * H3 + col) * BB + 16*w + lk*4) = vv;
    }
}

// ---------------------------------------------------------------------------
// K2: persistent GRU scan — in-band parity tags + cheap per-wave sentinels.
// 2 batch-groups x 16 slices; wave (mi,c) of WG (g,s) owns rows
// g*32+mi*16..+15, cols s*32+c*16..+15.  Per step: poll the 32 cluster
// sentinels (128B/sweep, cheap) -> ONE tagged data sweep (16KB, verified by
// bit14 tags; resweep only if fabric reordered sentinel ahead of data) ->
// MFMA -> gates -> tagged publish (dwordx2 via wave-local LDS transpose)
// -> own sentinel store.  No vmcnt drains on the publish side, no barriers.
// ---------------------------------------------------------------------------
__global__ __launch_bounds__(256) void k2_scan(
    const _Float16* __restrict__ xp, const _Float16* __restrict__ wsU,
    const float* __restrict__ bias, const unsigned long long* __restrict__ maskbits,
    char* __restrict__ hpub, float* __restrict__ hlast,
    unsigned int* __restrict__ flags)
{
    extern __shared__ char uLds[];
    const int tid = threadIdx.x;
    const int g = blockIdx.x >> 4;              // batch group (0..1)
    const int s = blockIdx.x & 15;              // hidden slice (0..15)
    const int w = tid >> 6, l = tid & 63;
    const int l15 = l & 15, lk = l >> 4;
    const int mi = w >> 1, c = w & 1;
    const int rb = g*32 + mi*16;                // wave's row band
    const int j  = s*SCOLS + c*16 + l15;        // this thread's hidden col
    const int b0 = rb + lk*4;
    const int cluster = (g*2 + mi) << 5;        // 32 producer waves per cluster
    unsigned short* scr = (unsigned short*)(uLds + UBYTES + w*512);

    // stage resident U slice (24 x 4KB)
    {
        const char* src = (const char*)wsU + (size_t)s * UBYTES;
        #pragma unroll
        for (int base = 0; base < UBYTES; base += 4096)
            GLL16(src + base + tid*16, uLds + base + tid*16);
    }

    // prologue prefetch: xp(0) -> even slot, xp(1) -> odd slot
    f16x4 xpe0, xpe1, xpe2, xpo0, xpo1, xpo2;
    unsigned long long mbe, mbo;
    {
        const _Float16* x0 = xp;
        xpe0 = *(const f16x4*)(x0 + (0*HH + j)*BB + b0);
        xpe1 = *(const f16x4*)(x0 + (1*HH + j)*BB + b0);
        xpe2 = *(const f16x4*)(x0 + (2*HH + j)*BB + b0);
        const _Float16* x1 = xp + (size_t)H3 * BB;
        xpo0 = *(const f16x4*)(x1 + (0*HH + j)*BB + b0);
        xpo1 = *(const f16x4*)(x1 + (1*HH + j)*BB + b0);
        xpo2 = *(const f16x4*)(x1 + (2*HH + j)*BB + b0);
        mbe = maskbits[0];
        mbo = maskbits[1];
    }
    const float b1z = bias[H3 + j];
    const float b1r = bias[H3 + HH + j];
    const float b1h = bias[H3 + 2*HH + j];
    float hold[4] = {};
    __syncthreads();   // U staged (only barrier in kernel)

    auto step = [&](int t, f16x4 xz4, f16x4 xr4, f16x4 xh4,
                    unsigned long long mbv) __attribute__((always_inline)) {
        f32x4 az = {}, ar = {}, ah = {};
        if (t > 0) {
            // cheap sentinel wait: 32 cluster flags, one per lane (dup >32)
            {
                const unsigned int* fp = flags + (cluster + (l & 31)) * 16;
                int n = 0;
                bool ok;
                do {
                    unsigned v = __hip_atomic_load(fp, __ATOMIC_RELAXED,
                                                   __HIP_MEMORY_SCOPE_AGENT);
                    ok = __all((int)(v >= (unsigned)t));
                } while (!ok && ++n < 100000);
            }
            // data sweep(s): verified by in-band tags (usually 1 sweep)
            const unsigned expm = ((t >> 1) & 1) ? 0x40004000u : 0u;
            const char* hsrc = hpub + (size_t)(t & 1) * HBYTES;
            unsigned long long hb = (unsigned long long)(hsrc + (rb + l15)*1024 + lk*16);
            u32x4 hf[16];
            int n = 0;
            while (true) {
#define LDH(i, off) asm volatile("global_load_dwordx4 %0, %1, off offset:" off " sc0 sc1" \
                                 : "=v"(hf[i]) : "v"(hb) : "memory")
                LDH(0,"0");    LDH(1,"64");   LDH(2,"128");  LDH(3,"192");
                LDH(4,"256");  LDH(5,"320");  LDH(6,"384");  LDH(7,"448");
                LDH(8,"512");  LDH(9,"576");  LDH(10,"640"); LDH(11,"704");
                LDH(12,"768"); LDH(13,"832"); LDH(14,"896"); LDH(15,"960");
#undef LDH
                asm volatile("s_waitcnt vmcnt(0)" ::: "memory");
                __builtin_amdgcn_sched_barrier(0);
                unsigned st = 0;
                #pragma unroll
                for (int p = 0; p < 16; ++p) {
                    #pragma unroll
                    for (int d = 0; d < 4; ++d)
                        st |= (hf[p][d] & 0x40004000u) ^ expm;
                }
                if (!__any((int)(st != 0))) break;
                if (++n > 2000) break;   // fast-fail bound
            }
            // strip tags -> clean f16 A-fragments
            #pragma unroll
            for (int p = 0; p < 16; ++p) {
                #pragma unroll
                for (int d = 0; d < 4; ++d) hf[p][d] &= 0xBFFFBFFFu;
            }
            __builtin_amdgcn_sched_barrier(0);
            #pragma unroll
            for (int ks = 0; ks < 16; ++ks) {
                f16x8 a = __builtin_bit_cast(f16x8, hf[ks]);
                const char* ub = uLds + (size_t)((ks*4 + lk)*UCOLS + c*16 + l15) * 16;
                f16x8 bz = *(const f16x8*)(ub);
                f16x8 br = *(const f16x8*)(ub + 512);    // +32 cols
                f16x8 bh = *(const f16x8*)(ub + 1024);   // +64 cols
                az = __builtin_amdgcn_mfma_f32_16x16x32_f16(a, bz, az, 0, 0, 0);
                ar = __builtin_amdgcn_mfma_f32_16x16x32_f16(a, br, ar, 0, 0, 0);
                ah = __builtin_amdgcn_mfma_f32_16x16x32_f16(a, bh, ah, 0, 0, 0);
            }
        }
        // gates
        #pragma unroll
        for (int i = 0; i < 4; ++i) {
            int row = b0 + i;
            float z  = 1.f / (1.f + __expf(-((float)xz4[i] + az[i] + b1z)));
            float rg = 1.f / (1.f + __expf(-((float)xr4[i] + ar[i] + b1r)));
            float ag = (float)xh4[i] + rg * (ah[i] + b1h);
            float hc = 1.f - 2.f / (__expf(2.f * ag) + 1.f);
            float hn = z * hold[i] + (1.f - z) * hc;
            if (!((mbv >> row) & 1ull)) hn = hold[i];
            hold[i] = hn;
        }
        if (t < SS - 1) {
            const unsigned tg = (((unsigned)(t + 1) >> 1) & 1u) << 14;
            // tag + stage into wave-private LDS tile [16 rows][16 cols]
            #pragma unroll
            for (int i = 0; i < 4; ++i) {
                unsigned hb16 = (unsigned)__builtin_bit_cast(unsigned short, (_Float16)hold[i]);
                if ((hb16 & 0x7FFFu) >= 0x3C00u) hb16 = (hb16 & 0x8000u) | 0x3BFFu;
                scr[(lk*4 + i)*16 + l15] = (unsigned short)(hb16 | tg);
            }
            // intra-wave transpose read (lockstep; compiler inserts lgkmcnt)
            u32x2 pk = *(const u32x2*)(scr + (l >> 2)*16 + (l & 3)*4);
            char* hnxt = hpub + (size_t)((t + 1) & 1) * HBYTES;
            unsigned long long pa = (unsigned long long)
                (hnxt + (size_t)(rb + (l >> 2))*1024 + (size_t)(s*SCOLS + c*16 + (l & 3)*4)*2);
            asm volatile("global_store_dwordx2 %0, %1, off sc0 sc1"
                         :: "v"(pa), "v"(pk) : "memory");
            // fire-and-forget sentinel (tags cover reordering)
            if (l == 0)
                __hip_atomic_store(flags + (cluster + (s*2 + c)) * 16,
                                   (unsigned)(t + 1),
                                   __ATOMIC_RELAXED, __HIP_MEMORY_SCOPE_AGENT);
        } else {
            #pragma unroll
            for (int i = 0; i < 4; ++i)
                hlast[(b0 + i)*HH + j] = hold[i];
        }
    };

    for (int t = 0; t < SS; t += 2) {
        step(t, xpe0, xpe1, xpe2, mbe);
        {   // prefetch even slot <- t+2
            int tl = (t + 2 < SS) ? t + 2 : SS - 1;
            const _Float16* xt = xp + (size_t)tl * H3 * BB;
            xpe0 = *(const f16x4*)(xt + (0*HH + j)*BB + b0);
            xpe1 = *(const f16x4*)(xt + (1*HH + j)*BB + b0);
            xpe2 = *(const f16x4*)(xt + (2*HH + j)*BB + b0);
            mbe = maskbits[tl];
        }
        step(t + 1, xpo0, xpo1, xpo2, mbo);
        {   // prefetch odd slot <- t+3
            int tl = (t + 3 < SS) ? t + 3 : SS - 1;
            const _Float16* xt = xp + (size_t)tl * H3 * BB;
            xpo0 = *(const f16x4*)(xt + (0*HH + j)*BB + b0);
            xpo1 = *(const f16x4*)(xt + (1*HH + j)*BB + b0);
            xpo2 = *(const f16x4*)(xt + (2*HH + j)*BB + b0);
            mbo = maskbits[tl];
        }
    }
}

// ---------------------------------------------------------------------------
// K3a: logits + per-WG softmax partials
// ---------------------------------------------------------------------------
__global__ __launch_bounds__(256) void k3_logits(
    const float* __restrict__ hin, const float* __restrict__ Wd,
    const float* __restrict__ bd, float* __restrict__ out,
    float* __restrict__ partials)
{
    const int nt = blockIdx.x;
    const int tid = threadIdx.x;
    __shared__ _Float16 hLds[64 * 512];

    for (int c = tid; c < 64 * 64; c += 256) {
        int row = c >> 6, kc = c & 63;
        const float* src = hin + row * HH + kc * 8;
        float4 f0 = *(const float4*)(src);
        float4 f1 = *(const float4*)(src + 4);
        f16x8 v;
        v[0]=(_Float16)f0.x; v[1]=(_Float16)f0.y; v[2]=(_Float16)f0.z; v[3]=(_Float16)f0.w;
        v[4]=(_Float16)f1.x; v[5]=(_Float16)f1.y; v[6]=(_Float16)f1.z; v[7]=(_Float16)f1.w;
        int byte = row * 1024 + ((kc * 16) ^ ((row & 7) << 4));
        *(f16x8*)((char*)hLds + byte) = v;
    }
    __syncthreads();

    const int w = tid >> 6, l = tid & 63;
    const int l15 = l & 15, lk = l >> 4;
    f32x4 acc[8] = {};

    for (int ks = 0; ks < 16; ++ks) {
        int arow = 16 * w + l15;
        int abyte = arow * 1024 + ((((ks * 32 + lk * 8) * 2)) ^ ((arow & 7) << 4));
        f16x8 aFrag = *(const f16x8*)((const char*)hLds + abyte);
        int krow = ks * 32 + lk * 8;
        #pragma unroll
        for (int ns = 0; ns < 8; ++ns) {
            int col = nt * 128 + ns * 16 + l15;
            f16x8 bFrag;
            if (col < VV) {
                #pragma unroll
                for (int i = 0; i < 8; ++i) bFrag[i] = (_Float16)Wd[(size_t)(krow + i) * VV + col];
            } else {
                #pragma unroll
                for (int i = 0; i < 8; ++i) bFrag[i] = (_Float16)0.f;
            }
            acc[ns] = __builtin_amdgcn_mfma_f32_16x16x32_f16(aFrag, bFrag, acc[ns], 0, 0, 0);
        }
    }

    float lg[8][4];
    float m[4] = {-3.4e38f, -3.4e38f, -3.4e38f, -3.4e38f};
    float ss[4] = {0.f, 0.f, 0.f, 0.f};
    #pragma unroll
    for (int ns = 0; ns < 8; ++ns) {
        int col = nt * 128 + ns * 16 + l15;
        bool ok = col < VV;
        float bv = ok ? bd[col] : 0.f;
        #pragma unroll
        for (int i = 0; i < 4; ++i) {
            int row = 16 * w + lk * 4 + i;
            float v = acc[ns][i] + bv;
            lg[ns][i] = ok ? v : -3.4e38f;
            if (ok) {
                out[(size_t)row * VV + col] = v;
                m[i] = fmaxf(m[i], v);
            }
        }
    }
    #pragma unroll
    for (int i = 0; i < 4; ++i) {
        #pragma unroll
        for (int ns = 0; ns < 8; ++ns)
            if (lg[ns][i] > -3.3e38f) ss[i] += __expf(lg[ns][i] - m[i]);
        for (int d = 1; d < 16; d <<= 1) {
            float m2 = __shfl_xor(m[i], d);
            float s2 = __shfl_xor(ss[i], d);
            float nM = fmaxf(m[i], m2);
            ss[i] = ss[i] * __expf(m[i] - nM) + s2 * __expf(m2 - nM);
            m[i] = nM;
        }
        if (l15 == 0) {
            int row = 16 * w + lk * 4 + i;
            partials[((size_t)nt * 64 + row) * 2 + 0] = m[i];
            partials[((size_t)nt * 64 + row) * 2 + 1] = ss[i];
        }
    }
}

__global__ __launch_bounds__(64) void k3_reduce(
    const float* __restrict__ partials, float* __restrict__ rowMS)
{
    int row = blockIdx.x, l = threadIdx.x;
    float M = -3.4e38f, Ssum = 0.f;
    for (int p = l; p < 393; p += 64) {
        float mp = partials[((size_t)p * 64 + row) * 2 + 0];
        float sp = partials[((size_t)p * 64 + row) * 2 + 1];
        float nM = fmaxf(M, mp);
        Ssum = Ssum * __expf(M - nM) + sp * __expf(mp - nM);
        M = nM;
    }
    for (int d = 1; d < 64; d <<= 1) {
        float m2 = __shfl_xor(M, d), s2 = __shfl_xor(Ssum, d);
        float nM = fmaxf(M, m2);
        Ssum = Ssum * __expf(M - nM) + s2 * __expf(m2 - nM);
        M = nM;
    }
    if (l == 0) { rowMS[row * 2] = M; rowMS[row * 2 + 1] = Ssum; }
}

__global__ __launch_bounds__(256) void k3_softmax(
    float* __restrict__ out, const float* __restrict__ rowMS)
{
    int col = blockIdx.x * 256 + threadIdx.x;
    int row = blockIdx.y;
    if (col < VV) {
        float M = rowMS[row * 2], Sv = rowMS[row * 2 + 1];
        size_t idx = (size_t)row * VV + col;
        out[idx] = __expf(out[idx] - M) / Sv;
    }
}

// ---------------------------------------------------------------------------
extern "C" void kernel_launch(void* const* d_in, const int* in_sizes, int n_in,
                              void* d_out, int out_size, void* d_ws, size_t ws_size,
                              hipStream_t stream) {
    const int*   tokens = (const int*)  d_in[0];
    const float* emb    = (const float*)d_in[1];
    const float* W      = (const float*)d_in[2];
    const float* U      = (const float*)d_in[3];
    const float* bias   = (const float*)d_in[4];
    const float* Wd     = (const float*)d_in[5];
    const float* bd     = (const float*)d_in[6];
    float* out = (float*)d_out;

    const size_t XP_BYTES   = (size_t)SS * BB * H3 * 2;     // 100,663,296
    const size_t WSU_BYTES  = (size_t)NSL * UBYTES;         // 1,572,864
    const size_t WSW_BYTES  = (size_t)32 * H3 * 8 * 2;      // 786,432
    const size_t HPUB_BYTES = 2 * (size_t)HBYTES;           // 131,072
    const size_t HLAST_BYTES= (size_t)BB * HH * 4;          // 131,072
    const size_t MASK_BYTES = (size_t)SS * 8;               // 4,096
    const size_t FLAG_BYTES = 8192;                         // 128 flags x 64B
    const size_t PART_BYTES = (size_t)393 * 64 * 2 * 4;     // 201,216

    char* ws = (char*)d_ws;
    _Float16* xp    = (_Float16*)ws;
    _Float16* wsU   = (_Float16*)(ws + XP_BYTES);
    _Float16* wsW   = (_Float16*)(ws + XP_BYTES + WSU_BYTES);
    char*     hpub  =            ws + XP_BYTES + WSU_BYTES + WSW_BYTES;
    float*    hlast = (float*)  (hpub + HPUB_BYTES);
    unsigned long long* maskb = (unsigned long long*)(hpub + HPUB_BYTES + HLAST_BYTES);
    unsigned int* flags = (unsigned int*)(hpub + HPUB_BYTES + HLAST_BYTES + MASK_BYTES);
    float* partials = (float*)(hpub + HPUB_BYTES + HLAST_BYTES + MASK_BYTES + FLAG_BYTES);
    float* rowMS    = (float*)(hpub + HPUB_BYTES + HLAST_BYTES + MASK_BYTES + FLAG_BYTES + PART_BYTES);

    hipFuncSetAttribute((const void*)k2_scan,
                        hipFuncAttributeMaxDynamicSharedMemorySize, UBYTES + SCRB);

    // tag-safe init: buf0 first expects tag1 -> init bit14=0 (0x00);
    //                buf1 first expects tag0 -> init bit14=1 (0x40)
    hipMemsetAsync(hpub, 0x00, HBYTES, stream);
    hipMemsetAsync(hpub + HBYTES, 0x40, HBYTES, stream);
    hipMemsetAsync(flags, 0, FLAG_BYTES, stream);

    kPackW<<<32 * H3 / 256, 256, 0, stream>>>(W, wsW);
    kPackU<<<NSL, 256, 0, stream>>>(U, wsU);
    kMask<<<2, 256, 0, stream>>>(tokens, maskb);
    k1_embed_proj<<<dim3(12, 512), 256, 0, stream>>>(tokens, emb, wsW, bias, xp);

    k2_scan<<<NWG, 256, UBYTES + SCRB, stream>>>(xp, wsU, bias, maskb, hpub, hlast, flags);

    k3_logits<<<393, 256, 0, stream>>>(hlast, Wd, bd, out, partials);
    k3_reduce<<<64, 64, 0, stream>>>(partials, rowMS);
    k3_softmax<<<dim3((VV + 255) / 256, BB), 256, 0, stream>>>(out, rowMS);
}